// Round 8
// baseline (597.169 us; speedup 1.0000x reference)
//
#include <hip/hip_runtime.h>

// Difference3DCostVolume: out[b,c,d,h,w] = l[b,c,h,w] - r[b,c,h,w-d], pad 1.0 for w<d
// Shapes: l,r [B=2, C=32, H=128, W=240] f32; out [B, C, D=48, H, W] f32.
// Write-BW bound: 377.5 MB out. Fill ceiling: ~6.9 TB/s. All 16B/thread variants: ~5.1 TB/s.
//
// R7: fill-clone burst stores. One block per (bc,d) slab (sequential 122.8 KB),
// 128 threads x 15 iters, each thread writes 4 consecutive f32x4 = 64 B per
// iteration (wave burst = 4 KB, 4 outstanding nt stores) — mimics rocclr
// fillBufferAligned's per-thread unroll. 60 % 4 == 0 so a 64 B chunk never
// crosses an h-row. r-window: 5 clamped f32x4 loads + funnel select on M=(-d)&3.

#define MAX_DISP 48
#define HH 128
#define NV 60                      // f32x4 per row
#define SLAB (HH * NV)             // 7680 f32x4 per (bc,d) slab

typedef float f32x4 __attribute__((ext_vector_type(4)));

template <int M>
__device__ __forceinline__ void slab_loop(
    const f32x4* __restrict__ l4, const f32x4* __restrict__ r4,
    f32x4* __restrict__ out4, size_t inbase, size_t obase, int d)
{
    // 1920 chunks of 64 B; 128 threads -> 15 iterations
    #pragma unroll 3
    for (int it = 0; it < 15; ++it) {
        const int c  = it * 128 + (int)threadIdx.x;   // chunk id 0..1919
        const int hh = c / 15;                        // h row
        const int p  = c - 15 * hh;                   // chunk within row 0..14
        const int w0 = 16 * p;                        // first element w
        const size_t rrow = inbase + (size_t)hh * NV;

        // floor((w0-d)/4); arithmetic shift gives floor for negatives
        const int q = (w0 - d) >> 2;                  // 4q + M == w0 - d

        // r window: 5 f32x4 (20 floats), clamped; OOB lanes masked by w>=d
        f32x4 R[5];
        #pragma unroll
        for (int j = 0; j < 5; ++j) {
            int idx = q + j;
            idx = idx < 0 ? 0 : (idx > NV - 1 ? NV - 1 : idx);
            R[j] = r4[rrow + idx];
        }

        // l: 4 consecutive f32x4 (64 B per lane, coalesced 4 KB per wave)
        f32x4 L[4];
        #pragma unroll
        for (int j = 0; j < 4; ++j) L[j] = l4[inbase + 4 * c + j];

        #pragma unroll
        for (int j2 = 0; j2 < 4; ++j2) {              // sub-f32x4, w = w0+4*j2+jj
            f32x4 o;
            #pragma unroll
            for (int jj = 0; jj < 4; ++jj) {
                const int e = M + 4 * j2 + jj;        // compile-time flat index into R
                const float rv = R[e >> 2][e & 3];
                o[jj] = (w0 + 4 * j2 + jj >= d) ? (L[j2][jj] - rv) : 1.0f;
            }
            __builtin_nontemporal_store(o, &out4[obase + 4 * c + j2]);
        }
    }
}

__global__ __launch_bounds__(128) void costvol_kernel(
    const f32x4* __restrict__ l4,
    const f32x4* __restrict__ r4,
    f32x4* __restrict__ out4)
{
    const int blk = blockIdx.x;          // bc*48 + d
    const int d   = blk % MAX_DISP;
    const int bc  = blk / MAX_DISP;

    const size_t inbase = (size_t)bc * SLAB;     // f32x4 index of (bc) input plane
    const size_t obase  = (size_t)blk * SLAB;    // contiguous output slab

    switch ((-d) & 3) {
        case 0: slab_loop<0>(l4, r4, out4, inbase, obase, d); break;
        case 1: slab_loop<1>(l4, r4, out4, inbase, obase, d); break;
        case 2: slab_loop<2>(l4, r4, out4, inbase, obase, d); break;
        case 3: slab_loop<3>(l4, r4, out4, inbase, obase, d); break;
    }
}

extern "C" void kernel_launch(void* const* d_in, const int* in_sizes, int n_in,
                              void* d_out, int out_size, void* d_ws, size_t ws_size,
                              hipStream_t stream) {
    const f32x4* l4 = (const f32x4*)d_in[0];
    const f32x4* r4 = (const f32x4*)d_in[1];
    f32x4* out4 = (f32x4*)d_out;

    const int nblocks = 64 * MAX_DISP;   // 3072 blocks, one 122.8 KB slab each
    costvol_kernel<<<nblocks, 128, 0, stream>>>(l4, r4, out4);
}

// Round 9
// 127.783 us; speedup vs baseline: 4.6733x; 4.6733x over previous
//
#include <hip/hip_runtime.h>

// Difference3DCostVolume: out[b,c,d,h,w] = l[b,c,h,w] - r[b,c,h,w-d], pad 1.0 for w<d
// Shapes: l,r [B=2, C=32, H=128, W=240] f32; out [B, C, D=48, H, W] f32.
// Write-BW bound: 377.5 MB out. Fill ceiling: ~6.9 TB/s (plain stores, sequential stream).
//
// R8: last untested matrix cell {plain stores x fully-sequential-per-block}.
// R5 structure exactly (one block per (bc,d), one contiguous 122.8 KB slab,
// 16 B/lane lane-consecutive stores), single flip: nt -> plain.

#define MAX_DISP 48
#define HH 128
#define NV 60                      // f32x4 per row
#define SLAB (HH * NV)             // 7680 f32x4 per (bc,d) slab

typedef float f32x4 __attribute__((ext_vector_type(4)));

template <int M>
__device__ __forceinline__ void slab_loop(
    const f32x4* __restrict__ l4, const f32x4* __restrict__ r4,
    f32x4* __restrict__ out4, size_t inbase, size_t obase, int d)
{
    for (int i = threadIdx.x; i < SLAB; i += 256) {
        const int h  = i / NV;
        const int v  = i - h * NV;
        const int w0 = 4 * v;
        const f32x4 lv = l4[inbase + i];

        const int idx = w0 - d;          // may be negative
        const int q   = idx >> 2;        // arithmetic shift = floor
        const size_t rrow = inbase + (size_t)h * NV;
        f32x4 A = (q >= 0) ? r4[rrow + q] : (f32x4){0.f, 0.f, 0.f, 0.f};
        const int qb = (q + 1 < NV - 1) ? q + 1 : NV - 1;
        f32x4 B = (q + 1 >= 0) ? r4[rrow + qb] : (f32x4){0.f, 0.f, 0.f, 0.f};

        f32x4 win;
        #pragma unroll
        for (int t = 0; t < 4; ++t)
            win[t] = (M + t < 4) ? A[M + t] : B[M + t - 4];

        f32x4 o;
        #pragma unroll
        for (int j = 0; j < 4; ++j)
            o[j] = (w0 + j >= d) ? (lv[j] - win[j]) : 1.0f;

        out4[obase + i] = o;             // PLAIN store, fully sequential stream
    }
}

__global__ __launch_bounds__(256) void costvol_kernel(
    const f32x4* __restrict__ l4,
    const f32x4* __restrict__ r4,
    f32x4* __restrict__ out4)
{
    const int blk = blockIdx.x;          // bc*48 + d
    const int d   = blk % MAX_DISP;
    const int bc  = blk / MAX_DISP;

    const size_t inbase = (size_t)bc * SLAB;     // f32x4 index of (bc) input plane
    const size_t obase  = (size_t)blk * SLAB;    // contiguous output slab

    switch ((-d) & 3) {
        case 0: slab_loop<0>(l4, r4, out4, inbase, obase, d); break;
        case 1: slab_loop<1>(l4, r4, out4, inbase, obase, d); break;
        case 2: slab_loop<2>(l4, r4, out4, inbase, obase, d); break;
        case 3: slab_loop<3>(l4, r4, out4, inbase, obase, d); break;
    }
}

extern "C" void kernel_launch(void* const* d_in, const int* in_sizes, int n_in,
                              void* d_out, int out_size, void* d_ws, size_t ws_size,
                              hipStream_t stream) {
    const f32x4* l4 = (const f32x4*)d_in[0];
    const f32x4* r4 = (const f32x4*)d_in[1];
    f32x4* out4 = (f32x4*)d_out;

    const int nblocks = 64 * MAX_DISP;   // 3072 blocks, one 122.8 KB slab each
    costvol_kernel<<<nblocks, 256, 0, stream>>>(l4, r4, out4);
}

// Round 10
// 77.701 us; speedup vs baseline: 7.6854x; 1.6445x over previous
//
#include <hip/hip_runtime.h>

// Difference3DCostVolume: out[b,c,d,h,w] = l[b,c,h,w] - r[b,c,h,w-d], pad 1.0 for w<d
// Shapes: l,r [B=2, C=32, H=128, W=240] f32; out [B, C, D=48, H, W] f32.
// Write-BW bound: 377.5 MB out, 15.7 MB in.
//
// FINAL (best measured: 77.48 us = 5.1 TB/s mixed): R2 structure.
// Matrix of {nt, plain} x {scattered streams, 15KB slabs, sequential} all
// land 77.5-80 us except plain+partial-line (89, RFO) and plain+sequential
// (128, L2 thrash vs 48x input reuse). nt + LDS-staged inputs + f32x4
// lane-consecutive stores is the winner; ~81% of D2D copy ceiling.

#define MAX_DISP 48
#define HH 128
#define WW 240
#define NV 60            // float4 per row
#define PAD4 12          // 12 float4 = 48 floats of front padding

typedef float f32x4 __attribute__((ext_vector_type(4)));

__global__ __launch_bounds__(256) void costvol_kernel(
    const f32x4* __restrict__ l4,
    const float* __restrict__ r,
    f32x4* __restrict__ out4)
{
    __shared__ float r_pad[48 + WW];   // 288 floats = 72 float4

    const int bch = blockIdx.x;        // bc*H + h
    const int h   = bch % HH;
    const int bc  = bch / HH;
    const int tid = threadIdx.x;
    const int v   = tid & 63;          // float4 index along W (0..59 active)
    const int kg  = tid >> 6;          // 0..3 -> d-group base

    // Stage r row into padded LDS; pad front with 0 (masked by w>=d anyway).
    if (tid < 48)  r_pad[tid] = 0.0f;
    if (tid < WW)  r_pad[48 + tid] = r[(size_t)bch * WW + tid];

    // l as float4, register-resident
    f32x4 lv = {0.f, 0.f, 0.f, 0.f};
    if (v < NV) lv = l4[(size_t)bch * NV + v];
    __syncthreads();

    if (v >= NV) return;

    const f32x4* rp4 = (const f32x4*)r_pad;
    const size_t  dstride4 = (size_t)HH * NV;            // float4 stride per d
    const int     w0 = 4 * v;                            // first w this thread owns

    #pragma unroll
    for (int iter = 0; iter < 3; ++iter) {
        const int k  = kg + 4 * iter;                    // wave-uniform
        const int d0 = 4 * k;

        // aligned, lane-consecutive LDS reads (conflict-free ds_read_b128)
        f32x4 A = rp4[PAD4 + v - k];                     // r[w0-d0 .. w0-d0+3]
        f32x4 B = rp4[PAD4 + v - k - 1];                 // r[w0-d0-4 .. w0-d0-1]

        size_t ob = ((size_t)(bc * MAX_DISP + d0) * HH + h) * NV + v;

        #pragma unroll
        for (int s = 0; s < 4; ++s) {                    // d = d0 + s
            f32x4 o;
            #pragma unroll
            for (int j = 0; j < 4; ++j) {                // w = w0 + j
                const int src = j - s;                   // compile-time
                float rv = (src >= 0) ? A[src] : B[4 + src];
                o[j] = (w0 + j >= d0 + s) ? (lv[j] - rv) : 1.0f;
            }
            __builtin_nontemporal_store(o, &out4[ob + (size_t)s * dstride4]);
        }
    }
}

extern "C" void kernel_launch(void* const* d_in, const int* in_sizes, int n_in,
                              void* d_out, int out_size, void* d_ws, size_t ws_size,
                              hipStream_t stream) {
    const f32x4* l4 = (const f32x4*)d_in[0];
    const float* r  = (const float*)d_in[1];
    f32x4* out4 = (f32x4*)d_out;

    const int nblocks = 2 * 32 * HH;   // B*C*H = 8192
    costvol_kernel<<<nblocks, 256, 0, stream>>>(l4, r, out4);
}